// Round 1
// baseline (555.467 us; speedup 1.0000x reference)
//
#include <hip/hip_runtime.h>
#include <hip/hip_bf16.h>

typedef __bf16 bf16;
typedef __bf16 bf16x4 __attribute__((ext_vector_type(4)));
typedef __bf16 bf16x8 __attribute__((ext_vector_type(8)));
typedef float  f32x2  __attribute__((ext_vector_type(2)));
typedef float  f32x4  __attribute__((ext_vector_type(4)));

static constexpr int NB  = 16;
static constexpr int NN  = 2048;
static constexpr int HID = 128;

// async 16B global -> LDS. LDS dest is wave-uniform base + lane*16.
__device__ __forceinline__ void gload_lds16(const bf16* g, bf16* l) {
    __builtin_amdgcn_global_load_lds(
        (const __attribute__((address_space(1))) unsigned int*)g,
        (__attribute__((address_space(3))) unsigned int*)l, 16, 0, 0);
}

// ---------------------------------------------------------------------------
// prep: W (128x128 fp32, [k][n]) -> WT bf16 [n][k], for all 3 layers
// ---------------------------------------------------------------------------
__global__ __launch_bounds__(256) void prep_wt(const float* __restrict__ W0,
                                               const float* __restrict__ W1,
                                               const float* __restrict__ W2,
                                               bf16* __restrict__ WT) {
    int l = blockIdx.x;
    const float* W = (l == 0) ? W0 : (l == 1) ? W1 : W2;
    bf16* out = WT + l * 128 * 128;
    int tid = threadIdx.x;
#pragma unroll
    for (int i = 0; i < 64; ++i) {
        int idx = i * 256 + tid;
        int k = idx >> 7, n = idx & 127;
        out[n * 128 + k] = (bf16)W[idx];
    }
}

// ---------------------------------------------------------------------------
// prep: x (16,2048,128) fp32 -> xT (16,128,2048) bf16  (B-operand for L0 big)
// ---------------------------------------------------------------------------
__global__ __launch_bounds__(256) void prep_xt(const float* __restrict__ x,
                                               bf16* __restrict__ xT) {
    __shared__ bf16 T[128 * 136];
    const int blk = blockIdx.x;          // 256 blocks: 16 tiles x 16 batches
    const int b = blk >> 4, node0 = (blk & 15) * 128;
    const int tid = threadIdx.x;
    const float* xb = x + ((size_t)b * NN + node0) * HID;
#pragma unroll
    for (int i = 0; i < 64; ++i) {
        int idx = i * 256 + tid;
        int node = idx >> 7, hid = idx & 127;
        T[hid * 136 + node] = (bf16)xb[(size_t)node * HID + hid];
    }
    __syncthreads();
    bf16* ob = xT + (size_t)b * HID * NN + node0;
#pragma unroll
    for (int i = 0; i < 8; ++i) {
        int flat = i * 2048 + tid * 8;
        int hid = flat >> 7, node = flat & 127;
        *(bf16x8*)(ob + (size_t)hid * NN + node) = *(const bf16x8*)(T + hid * 136 + node);
    }
}

// ---------------------------------------------------------------------------
// big GEMM (pure): g[b] (2048x128) = adj[b](2048x2048) @ h[b](2048x128)
// BM=64, BN=128(full), BK=64, 32 iters. 256 thr = 4 waves, wave-tile 32x64.
// LDS: physical 16B chunk p = row*8 + (colblk ^ (row&7)) for both tiles.
// v2: XCD-aware block swizzle (each XCD owns 2 batches -> B panel L2-resident)
//     + 2-phase double-buffered pipeline (stage k+1 before computing k, one
//     barrier per K-step) so load latency hides under ds_read+MFMA.
// AMODE 1: A from fp32 adj (regs, issued early; cvt+ds_write+adjB store late).
// AMODE 2: A from adjB via async global_load_lds (swizzle on src addr).
// ---------------------------------------------------------------------------
template<int AMODE>
__global__ __launch_bounds__(256, 2) void big_gemm(const float* __restrict__ Af,
                                                   bf16* __restrict__ adjB,
                                                   const bf16* __restrict__ Bt,
                                                   bf16* __restrict__ g) {
    __shared__ bf16 As[2][64 * 64];      // 2 x 8 KB
    __shared__ bf16 Bs[2][128 * 64];     // 2 x 16 KB

    const int tid  = threadIdx.x;
    const int wave = tid >> 6, lane = tid & 63;
    const int c0 = lane & 15, q = lane >> 4;

    // XCD-aware swizzle: 1-D grid of 512; consecutive ids round-robin XCDs.
    // xcd = blk&7 owns batches {2*xcd, 2*xcd+1}; 32 m-tiles per batch.
    const int blk = blockIdx.x;
    const int xcd = blk & 7, jj = blk >> 3;
    const int b   = xcd * 2 + (jj & 1);
    const int m0  = (jj >> 1) * 64;

    const size_t abase = (size_t)b * NN * NN;
    const bf16* Btb = Bt + (size_t)b * HID * NN;
    const int wm = wave >> 1, wn = wave & 1;

    f32x4 acc[2][4] = {};

    int prow[4], pcb[4];
#pragma unroll
    for (int j = 0; j < 4; ++j) {
        int p = j * 256 + wave * 64 + lane;
        prow[j] = p >> 3;
        pcb[j]  = (p & 7) ^ (prow[j] & 7);
    }
    const int ldsbase = wave * 512;   // elems: chunk base (wave*64)*8

    int grow_[2], gcb_[2];
#pragma unroll
    for (int j = 0; j < 2; ++j) {
        int gi = j * 256 + tid;
        grow_[j] = gi >> 3;
        gcb_[j]  = gi & 7;
    }

    auto stageB = [&](int buf, int k0) {
#pragma unroll
        for (int j = 0; j < 4; ++j)
            gload_lds16(Btb + (size_t)prow[j] * NN + k0 + pcb[j] * 8,
                        &Bs[buf][j * 2048 + ldsbase]);
    };
    auto stageA_async = [&](int buf, int k0) {
#pragma unroll
        for (int j = 0; j < 2; ++j)
            gload_lds16(adjB + abase + (size_t)(m0 + prow[j]) * NN + k0 + pcb[j] * 8,
                        &As[buf][j * 2048 + ldsbase]);
    };
    auto loadA_f32 = [&](int k0, f32x4* va, f32x4* vb) {
#pragma unroll
        for (int j = 0; j < 2; ++j) {
            const float* src = Af + abase + (size_t)(m0 + grow_[j]) * NN + k0 + gcb_[j] * 8;
            va[j] = *(const f32x4*)src;
            vb[j] = *(const f32x4*)(src + 4);
        }
    };
    auto writeA = [&](int buf, int k0, const f32x4* va, const f32x4* vb) {
#pragma unroll
        for (int j = 0; j < 2; ++j) {
            bf16x8 o = {(bf16)va[j].x, (bf16)va[j].y, (bf16)va[j].z, (bf16)va[j].w,
                        (bf16)vb[j].x, (bf16)vb[j].y, (bf16)vb[j].z, (bf16)vb[j].w};
            *(bf16x8*)(&As[buf][(grow_[j] * 8 + (gcb_[j] ^ (grow_[j] & 7))) * 8]) = o;
            *(bf16x8*)(adjB + abase + (size_t)(m0 + grow_[j]) * NN + k0 + gcb_[j] * 8) = o;
        }
    };
    auto compute = [&](int buf) {
#pragma unroll
        for (int ks = 0; ks < 2; ++ks) {
            bf16x8 af[2], bfr[4];
#pragma unroll
            for (int mt = 0; mt < 2; ++mt) {
                int row = wm * 32 + mt * 16 + c0;
                int cb  = (ks * 4 + q) ^ (row & 7);
                af[mt] = *(const bf16x8*)(&As[buf][row * 64 + cb * 8]);
            }
#pragma unroll
            for (int nt = 0; nt < 4; ++nt) {
                int row = wn * 64 + nt * 16 + c0;
                int cb  = (ks * 4 + q) ^ (row & 7);
                bfr[nt] = *(const bf16x8*)(&Bs[buf][row * 64 + cb * 8]);
            }
#pragma unroll
            for (int mt = 0; mt < 2; ++mt)
#pragma unroll
                for (int nt = 0; nt < 4; ++nt)
                    acc[mt][nt] = __builtin_amdgcn_mfma_f32_16x16x32_bf16(af[mt], bfr[nt], acc[mt][nt], 0, 0, 0);
        }
    };

    // ---- prologue: stage K-tile 0 into buffer 0 ----
    f32x4 va[2], vb[2];
    if constexpr (AMODE == 1) {
        loadA_f32(0, va, vb);
        stageB(0, 0);
        writeA(0, 0, va, vb);
    } else {
        stageA_async(0, 0);
        stageB(0, 0);
    }
    __syncthreads();

    // ---- 2-phase main loop: stage kk+1 (buf^1) while computing kk (buf) ----
    int cur = 0;
    for (int kk = 0; kk < 32; ++kk) {
        const int k1 = (kk + 1) * 64;
        if constexpr (AMODE == 1) {
            if (kk < 31) {
                loadA_f32(k1, va, vb);       // issue early: latency under MFMA
                stageB(cur ^ 1, k1);
            }
            compute(cur);
            if (kk < 31)
                writeA(cur ^ 1, k1, va, vb); // cvt + ds_write + adjB store late
        } else {
            if (kk < 31) {
                stageA_async(cur ^ 1, k1);
                stageB(cur ^ 1, k1);
            }
            compute(cur);
        }
        __syncthreads();
        cur ^= 1;
    }

    bf16* gb = g + ((size_t)b * NN + m0) * HID;
#pragma unroll
    for (int mt = 0; mt < 2; ++mt)
#pragma unroll
        for (int r = 0; r < 4; ++r) {
            int m = wm * 32 + mt * 16 + q * 4 + r;
#pragma unroll
            for (int nt = 0; nt < 4; ++nt) {
                int n = wn * 64 + nt * 16 + c0;
                gb[(size_t)m * HID + n] = (bf16)acc[mt][nt][r];
            }
        }
}

// ---------------------------------------------------------------------------
// small GEMM + fused bias/LN/ReLU: h' = relu(LN(g @ W + b))
//   g: (32768,128) bf16 row-major (k-contig). WT: [n][k] bf16.
//   FINAL=false: write hT[b][n][node] (transposed, for next big's B operand)
//   FINAL=true : write fp32 row-major to d_out
// ---------------------------------------------------------------------------
template<bool FINAL>
__global__ __launch_bounds__(256) void small_ln(const bf16* __restrict__ gin,
                                                const bf16* __restrict__ WT,
                                                const float* __restrict__ bias,
                                                const float* __restrict__ gamma,
                                                const float* __restrict__ betap,
                                                bf16* __restrict__ hT,
                                                float* __restrict__ outF) {
    __shared__ bf16 smem[2 * 128 * 72];
    bf16* As = smem;
    bf16* Bs = smem + 128 * 72;

    const int tid  = threadIdx.x;
    const int wave = tid >> 6, lane = tid & 63;
    const int c0 = lane & 15, q = lane >> 4;
    const int blk = blockIdx.x;
    const int row_g0 = blk * 128;

    f32x4 acc[2][8] = {};

    for (int kk = 0; kk < 2; ++kk) {
        const int k0 = kk * 64;
#pragma unroll
        for (int i = 0; i < 4; ++i) {
            int flat = i * 2048 + tid * 8;
            int row = flat >> 6, col = flat & 63;
            bf16x8 v = *(const bf16x8*)(gin + (size_t)(row_g0 + row) * HID + k0 + col);
            *(bf16x8*)(As + row * 72 + col) = v;
        }
#pragma unroll
        for (int i = 0; i < 4; ++i) {
            int flat = i * 2048 + tid * 8;
            int row = flat >> 6, col = flat & 63;
            bf16x8 v = *(const bf16x8*)(WT + (size_t)row * 128 + k0 + col);
            *(bf16x8*)(Bs + row * 72 + col) = v;
        }
        __syncthreads();
#pragma unroll
        for (int ks = 0; ks < 2; ++ks) {
            bf16x8 af[2];
#pragma unroll
            for (int mt = 0; mt < 2; ++mt)
                af[mt] = *(const bf16x8*)(As + (wave * 32 + mt * 16 + c0) * 72 + ks * 32 + q * 8);
#pragma unroll
            for (int nt = 0; nt < 8; ++nt) {
                bf16x8 bfr = *(const bf16x8*)(Bs + (nt * 16 + c0) * 72 + ks * 32 + q * 8);
#pragma unroll
                for (int mt = 0; mt < 2; ++mt)
                    acc[mt][nt] = __builtin_amdgcn_mfma_f32_16x16x32_bf16(af[mt], bfr, acc[mt][nt], 0, 0, 0);
            }
        }
        __syncthreads();
    }

    // epilogue: bias + LN over n(128) + ReLU
    float bv[8], gv[8], bev[8];
#pragma unroll
    for (int nt = 0; nt < 8; ++nt) {
        int n = nt * 16 + c0;
        bv[nt] = bias[n]; gv[nt] = gamma[n]; bev[nt] = betap[n];
    }
    bf16* Cs = smem;   // reuse (post-barrier)
#pragma unroll
    for (int mt = 0; mt < 2; ++mt) {
#pragma unroll
        for (int r = 0; r < 4; ++r) {
            float v[8], s1 = 0.f, s2 = 0.f;
#pragma unroll
            for (int nt = 0; nt < 8; ++nt) {
                float xv = acc[mt][nt][r] + bv[nt];
                v[nt] = xv; s1 += xv; s2 += xv * xv;
            }
#pragma unroll
            for (int off = 1; off < 16; off <<= 1) {
                s1 += __shfl_xor(s1, off);
                s2 += __shfl_xor(s2, off);
            }
            float mu  = s1 * (1.f / 128.f);
            float var = s2 * (1.f / 128.f) - mu * mu;
            float rs  = rsqrtf(var + 1e-5f);
            int m = wave * 32 + mt * 16 + q * 4 + r;   // local row in [0,128)
            if constexpr (FINAL) {
                size_t rowoff = ((size_t)row_g0 + m) * HID;
#pragma unroll
                for (int nt = 0; nt < 8; ++nt) {
                    float o = fmaxf((v[nt] - mu) * rs * gv[nt] + bev[nt], 0.f);
                    outF[rowoff + nt * 16 + c0] = o;
                }
            } else {
#pragma unroll
                for (int nt = 0; nt < 8; ++nt) {
                    float o = fmaxf((v[nt] - mu) * rs * gv[nt] + bev[nt], 0.f);
                    Cs[(nt * 16 + c0) * 136 + m] = (bf16)o;
                }
            }
        }
    }
    if constexpr (!FINAL) {
        __syncthreads();
        const int b = blk >> 4, row0 = (blk & 15) * 128;
        bf16* outp = hT + (size_t)b * HID * NN;
#pragma unroll
        for (int i = 0; i < 8; ++i) {
            int flat = i * 2048 + tid * 8;
            int n = flat >> 7, mm = flat & 127;
            *(bf16x8*)(outp + (size_t)n * NN + row0 + mm) = *(const bf16x8*)(Cs + n * 136 + mm);
        }
    }
}

// ---------------------------------------------------------------------------
extern "C" void kernel_launch(void* const* d_in, const int* in_sizes, int n_in,
                              void* d_out, int out_size, void* d_ws, size_t ws_size,
                              hipStream_t stream) {
    const float* x   = (const float*)d_in[0];
    const float* adj = (const float*)d_in[1];
    const float* W[3]  = {(const float*)d_in[2],  (const float*)d_in[6],  (const float*)d_in[10]};
    const float* bb[3] = {(const float*)d_in[3],  (const float*)d_in[7],  (const float*)d_in[11]};
    const float* gg[3] = {(const float*)d_in[4],  (const float*)d_in[8],  (const float*)d_in[12]};
    const float* be[3] = {(const float*)d_in[5],  (const float*)d_in[9],  (const float*)d_in[13]};

    char* ws = (char*)d_ws;
    size_t off = 0;
    auto alloc = [&](size_t bytes) { char* p = ws + off; off = (off + bytes + 255) & ~(size_t)255; return p; };
    bf16* WT   = (bf16*)alloc((size_t)3 * 128 * 128 * 2);
    bf16* xT   = (bf16*)alloc((size_t)NB * HID * NN * 2);   // 8 MiB
    bf16* hT   = (bf16*)alloc((size_t)NB * HID * NN * 2);   // 8 MiB
    bf16* gbuf = (bf16*)alloc((size_t)NB * NN * HID * 2);   // 8 MiB
    bf16* adjB = (bf16*)alloc((size_t)NB * NN * NN * 2);    // 128 MiB

    float* outF = (float*)d_out;

    prep_wt<<<3, 256, 0, stream>>>(W[0], W[1], W[2], WT);
    prep_xt<<<256, 256, 0, stream>>>(x, xT);

    // ---- layer 0 (fp32 adj read fused with bf16 conversion/side-write) ----
    big_gemm<1><<<512, 256, 0, stream>>>(adj, adjB, xT, gbuf);
    small_ln<false><<<256, 256, 0, stream>>>(gbuf, WT, bb[0], gg[0], be[0], hT, nullptr);
    // ---- layer 1 ----
    big_gemm<2><<<512, 256, 0, stream>>>(adj, adjB, hT, gbuf);
    small_ln<false><<<256, 256, 0, stream>>>(gbuf, WT + 128 * 128, bb[1], gg[1], be[1], hT, nullptr);
    // ---- layer 2 ----
    big_gemm<2><<<512, 256, 0, stream>>>(adj, adjB, hT, gbuf);
    small_ln<true><<<256, 256, 0, stream>>>(gbuf, WT + 2 * 128 * 128, bb[2], gg[2], be[2], nullptr, outF);
}

// Round 3
// 494.652 us; speedup vs baseline: 1.1229x; 1.1229x over previous
//
#include <hip/hip_runtime.h>
#include <hip/hip_bf16.h>

typedef __bf16 bf16;
typedef __bf16 bf16x8 __attribute__((ext_vector_type(8)));
typedef float  f32x4  __attribute__((ext_vector_type(4)));

static constexpr int NB  = 16;
static constexpr int NN  = 2048;
static constexpr int HID = 128;

// async 16B global -> LDS. LDS dest is wave-uniform base (+ lane*16 in HW);
// global src address IS per-lane (must carry the lane term!).
__device__ __forceinline__ void gload_lds16(const bf16* g, bf16* l) {
    __builtin_amdgcn_global_load_lds(
        (const __attribute__((address_space(1))) unsigned int*)g,
        (__attribute__((address_space(3))) unsigned int*)l, 16, 0, 0);
}
__device__ __forceinline__ void memfence() { asm volatile("" ::: "memory"); }

// ---------------------------------------------------------------------------
// Tiled layouts ("LDS images", 16 KB tiles of 1024 16B-chunks):
//   A-tile (128 rows x 64 k): chunk p = row*8 + (kc ^ (row&7)), kc = k/8
//   B-tile (128 n   x 64 k): same formula with n as row
//   adjT[b][mtile(16)][kk(32)] tiles ; xTt/hTt[b][kk(32)] tiles
//   WTg per layer: 2048 chunks: chunk = n*16 + half*8 + (kc8 ^ (n&7)),
//     half = k>>6, kc8 = (k&63)>>3  (k-contig bf16x8 fragments of W^T[n][k])
// ---------------------------------------------------------------------------

// prep: W (128x128 fp32, [k][n]) -> swizzled WT tiles, for all 3 layers
__global__ __launch_bounds__(256) void prep_wt(const float* __restrict__ W0,
                                               const float* __restrict__ W1,
                                               const float* __restrict__ W2,
                                               bf16* __restrict__ WTg) {
    int l = blockIdx.x;
    const float* W = (l == 0) ? W0 : (l == 1) ? W1 : W2;
    bf16* out = WTg + l * 16384;
    int tid = threadIdx.x;
#pragma unroll
    for (int i = 0; i < 8; ++i) {
        int p = i * 256 + tid;                 // [0,2048)
        int n = p >> 4, half = (p >> 3) & 1, cs = p & 7;
        int kc = cs ^ (n & 7);
        int kbase = half * 64 + kc * 8;
        bf16x8 o;
#pragma unroll
        for (int r = 0; r < 8; ++r) o[r] = (bf16)W[(kbase + r) * 128 + n];
        *(bf16x8*)(out + p * 8) = o;
    }
}

// prep: x (16,2048,128) fp32 -> xTt tiled bf16 B-tiles
__global__ __launch_bounds__(256) void prep_xt(const float* __restrict__ x,
                                               bf16* __restrict__ xTt) {
    __shared__ bf16 T[128 * 136];
    const int blk = blockIdx.x;            // 256 blocks: 16 node-tiles x 16 b
    const int b = blk >> 4, node0 = (blk & 15) * 128;
    const int tid = threadIdx.x;
    const float* xb = x + ((size_t)b * NN + node0) * HID;
#pragma unroll
    for (int i = 0; i < 64; ++i) {
        int idx = i * 256 + tid;
        int node = idx >> 7, hid = idx & 127;
        T[hid * 136 + node] = (bf16)xb[(size_t)node * HID + hid];
    }
    __syncthreads();
#pragma unroll
    for (int i = 0; i < 8; ++i) {
        int p = i * 256 + tid;                 // [0,2048) chunks (2 tiles)
        int half = p >> 10, p1 = p & 1023;
        int n = p1 >> 3, cs = p1 & 7, c = cs ^ (n & 7), m = half * 64 + c * 8;
        *(bf16x8*)(xTt + ((size_t)b * 32 + (node0 >> 6) + half) * 8192 + p1 * 8)
            = *(const bf16x8*)(T + n * 136 + m);
    }
}

// ---------------------------------------------------------------------------
// fused layer: g = adj[b] @ h[b]  (BM=128, BN=128, BK=64, 32 K-steps, 8 waves)
//   then epilogue: h' = relu(LN(g @ W + bias)), written as tiled B for next.
// AMODE 1: A from fp32 adj (regs, issued early; cvt+ds/global-store late),
//          side-writes tiled adjT.  __syncthreads pipeline.
// AMODE 2: A from adjT via linear global_load_lds; counted vmcnt(4) 2-deep
//          pipeline with raw barriers (all staging loads are linear 16KB).
// ---------------------------------------------------------------------------
template<int AMODE, bool FINAL>
__global__ __launch_bounds__(512, 2) void fused_layer(
        const float* __restrict__ Af, bf16* __restrict__ adjT,
        const bf16* __restrict__ Bt, const bf16* __restrict__ WTg,
        const float* __restrict__ bias, const float* __restrict__ gam,
        const float* __restrict__ bet, bf16* __restrict__ hOut,
        float* __restrict__ outF) {
    // [0,32K): A/B double-buffer (4x 8192 elems). [32K,48K): WT. (elems)
    __shared__ __align__(16) bf16 lds[49152];
    bf16* WTl = lds + 32768;

    const int tid = threadIdx.x, wave = tid >> 6, lane = tid & 63;
    const int c0 = lane & 15, q = lane >> 4;
    const int blk = blockIdx.x, xcd = blk & 7, jj = blk >> 3;
    const int b = xcd * 2 + (jj & 1);       // each XCD owns 2 batches
    const int mtile = jj >> 1, m0 = mtile * 128;
    const int wm = wave >> 1, wn = wave & 1;

    const bf16* Btb = Bt + (size_t)b * 32 * 8192;
    bf16* Atl = adjT + ((size_t)b * 16 + mtile) * 32 * 8192;

    f32x4 acc[2][4] = {};

    // stage WT (2048 chunks, linear): 4 loads/wave; global src carries +lane
#pragma unroll
    for (int j = 0; j < 4; ++j) {
        int cb = j * 512 + wave * 64;
        gload_lds16(WTg + (size_t)(cb + lane) * 8, WTl + cb * 8);
    }

    auto stageA2 = [&](int buf, int kk) {    // 2 loads/wave, linear 16KB
#pragma unroll
        for (int j = 0; j < 2; ++j) {
            int cb = j * 512 + wave * 64;
            gload_lds16(Atl + (size_t)kk * 8192 + (size_t)(cb + lane) * 8,
                        lds + buf * 16384 + cb * 8);
        }
    };
    auto stageB2 = [&](int buf, int kk) {    // 2 loads/wave, linear 16KB
#pragma unroll
        for (int j = 0; j < 2; ++j) {
            int cb = j * 512 + wave * 64;
            gload_lds16(Btb + (size_t)kk * 8192 + (size_t)(cb + lane) * 8,
                        lds + buf * 16384 + 8192 + cb * 8);
        }
    };
    auto compute = [&](int buf) {
        const bf16* As = lds + buf * 16384;
        const bf16* Bs = As + 8192;
#pragma unroll
        for (int ks = 0; ks < 2; ++ks) {
            bf16x8 af[2], bf_[4];
#pragma unroll
            for (int mt = 0; mt < 2; ++mt) {
                int row = wm * 32 + mt * 16 + c0;
                int cb = (ks * 4 + q) ^ (row & 7);
                af[mt] = *(const bf16x8*)(As + row * 64 + cb * 8);
            }
#pragma unroll
            for (int nt = 0; nt < 4; ++nt) {
                int row = wn * 64 + nt * 16 + c0;
                int cb = (ks * 4 + q) ^ (row & 7);
                bf_[nt] = *(const bf16x8*)(Bs + row * 64 + cb * 8);
            }
#pragma unroll
            for (int mt = 0; mt < 2; ++mt)
#pragma unroll
                for (int nt = 0; nt < 4; ++nt)
                    acc[mt][nt] = __builtin_amdgcn_mfma_f32_16x16x32_bf16(
                        af[mt], bf_[nt], acc[mt][nt], 0, 0, 0);
        }
    };

    if constexpr (AMODE == 1) {
        int grow[2], gcb[2];
#pragma unroll
        for (int j = 0; j < 2; ++j) {
            int gi = j * 512 + tid;
            grow[j] = gi >> 3; gcb[j] = gi & 7;
        }
        f32x4 va[2], vb[2];
        auto loadA = [&](int kk) {
#pragma unroll
            for (int j = 0; j < 2; ++j) {
                const float* s = Af + (size_t)b * NN * NN
                               + (size_t)(m0 + grow[j]) * NN + kk * 64 + gcb[j] * 8;
                va[j] = *(const f32x4*)s;
                vb[j] = *(const f32x4*)(s + 4);
            }
        };
        auto writeA = [&](int buf, int kk) {
#pragma unroll
            for (int j = 0; j < 2; ++j) {
                bf16x8 o = {(bf16)va[j].x, (bf16)va[j].y, (bf16)va[j].z, (bf16)va[j].w,
                            (bf16)vb[j].x, (bf16)vb[j].y, (bf16)vb[j].z, (bf16)vb[j].w};
                int ch = grow[j] * 8 + (gcb[j] ^ (grow[j] & 7));
                *(bf16x8*)(lds + buf * 16384 + ch * 8) = o;
                *(bf16x8*)(Atl + (size_t)kk * 8192 + ch * 8) = o;  // tiled side-write
            }
        };
        loadA(0); stageB2(0, 0); writeA(0, 0);
        __syncthreads();
        int cur = 0;
        for (int kk = 0; kk < 32; ++kk) {
            if (kk < 31) { loadA(kk + 1); stageB2(cur ^ 1, kk + 1); }
            compute(cur);
            if (kk < 31) writeA(cur ^ 1, kk + 1);
            __syncthreads();
            cur ^= 1;
        }
    } else {
        // prologue: WT(4) + tile0(4) + tile1(4) outstanding per wave
        stageA2(0, 0); stageB2(0, 0);
        stageA2(1, 1); stageB2(1, 1);
#pragma unroll 1
        for (int kk = 0; kk < 32; ++kk) {
            // in-order VMEM retirement: <=4 outstanding => tile kk landed
            if (kk < 31) asm volatile("s_waitcnt vmcnt(4)" ::: "memory");
            else         asm volatile("s_waitcnt vmcnt(0)" ::: "memory");
            __builtin_amdgcn_s_barrier();
            memfence();
            compute(kk & 1);
            memfence();
            __builtin_amdgcn_s_barrier();   // all waves done reading buf kk&1
            if (kk < 30) { stageA2(kk & 1, kk + 2); stageB2(kk & 1, kk + 2); }
        }
        __syncthreads();
    }

    // ---- epilogue: store g-tile bf16 to LDS [128][136] (dbuf area dead) ----
    bf16* G = lds;
#pragma unroll
    for (int mt = 0; mt < 2; ++mt)
#pragma unroll
        for (int r = 0; r < 4; ++r) {
            int row = wm * 32 + mt * 16 + q * 4 + r;
#pragma unroll
            for (int nt = 0; nt < 4; ++nt) {
                int col = wn * 64 + nt * 16 + c0;
                G[row * 136 + col] = (bf16)acc[mt][nt][r];
            }
        }
    __syncthreads();

    // ---- W-GEMM: h(128x128) = G @ W ; wave w owns rows [w*16, w*16+16) ----
    f32x4 a2[8] = {};
    {
        const int gr = wave * 16 + c0;
#pragma unroll
        for (int ks = 0; ks < 4; ++ks) {
            bf16x8 af = *(const bf16x8*)(G + gr * 136 + ks * 32 + q * 8);
#pragma unroll
            for (int nt = 0; nt < 8; ++nt) {
                int n = nt * 16 + c0;
                int ch = n * 16 + (ks >> 1) * 8 + ((((ks & 1) << 2) | q) ^ (n & 7));
                bf16x8 bw = *(const bf16x8*)(WTl + ch * 8);
                a2[nt] = __builtin_amdgcn_mfma_f32_16x16x32_bf16(af, bw, a2[nt], 0, 0, 0);
            }
        }
    }

    // ---- bias + LN(over n=128) + ReLU ----
    float bv[8], gv[8], ev[8];
#pragma unroll
    for (int nt = 0; nt < 8; ++nt) {
        int n = nt * 16 + c0;
        bv[nt] = bias[n]; gv[nt] = gam[n]; ev[nt] = bet[n];
    }
    bf16* Cs = lds;  // reuse G area for transpose staging (post-barrier)
    if constexpr (!FINAL) __syncthreads();   // all W-GEMM reads of G done
#pragma unroll
    for (int r = 0; r < 4; ++r) {
        float v[8], s1 = 0.f, s2 = 0.f;
#pragma unroll
        for (int nt = 0; nt < 8; ++nt) {
            float xv = a2[nt][r] + bv[nt];
            v[nt] = xv; s1 += xv; s2 += xv * xv;
        }
#pragma unroll
        for (int off = 1; off < 16; off <<= 1) {
            s1 += __shfl_xor(s1, off);
            s2 += __shfl_xor(s2, off);
        }
        float mu = s1 * (1.f / 128.f);
        float var = s2 * (1.f / 128.f) - mu * mu;
        float rs = rsqrtf(var + 1e-5f);
        int row = wave * 16 + q * 4 + r;      // local row in [0,128)
        if constexpr (FINAL) {
            size_t ro = ((size_t)b * NN + m0 + row) * HID;
#pragma unroll
            for (int nt = 0; nt < 8; ++nt) {
                float o = fmaxf((v[nt] - mu) * rs * gv[nt] + ev[nt], 0.f);
                outF[ro + nt * 16 + c0] = o;
            }
        } else {
#pragma unroll
            for (int nt = 0; nt < 8; ++nt) {
                float o = fmaxf((v[nt] - mu) * rs * gv[nt] + ev[nt], 0.f);
                Cs[(nt * 16 + c0) * 136 + row] = (bf16)o;
            }
        }
    }
    if constexpr (!FINAL) {
        __syncthreads();
        // write 2 tiled B-tiles (kk = mtile*2, mtile*2+1), fully linear
#pragma unroll
        for (int i = 0; i < 4; ++i) {
            int p = i * 512 + tid;            // [0,2048)
            int half = p >> 10, p1 = p & 1023;
            int n = p1 >> 3, cs = p1 & 7, c = cs ^ (n & 7), m = half * 64 + c * 8;
            *(bf16x8*)(hOut + ((size_t)b * 32 + mtile * 2 + half) * 8192 + p1 * 8)
                = *(const bf16x8*)(Cs + n * 136 + m);
        }
    }
}

// ---------------------------------------------------------------------------
extern "C" void kernel_launch(void* const* d_in, const int* in_sizes, int n_in,
                              void* d_out, int out_size, void* d_ws, size_t ws_size,
                              hipStream_t stream) {
    const float* x   = (const float*)d_in[0];
    const float* adj = (const float*)d_in[1];
    const float* W[3]  = {(const float*)d_in[2],  (const float*)d_in[6],  (const float*)d_in[10]};
    const float* bb[3] = {(const float*)d_in[3],  (const float*)d_in[7],  (const float*)d_in[11]};
    const float* gg[3] = {(const float*)d_in[4],  (const float*)d_in[8],  (const float*)d_in[12]};
    const float* be[3] = {(const float*)d_in[5],  (const float*)d_in[9],  (const float*)d_in[13]};

    char* ws = (char*)d_ws;
    size_t off = 0;
    auto alloc = [&](size_t bytes) {
        char* p = ws + off; off = (off + bytes + 255) & ~(size_t)255; return p;
    };
    bf16* WTg  = (bf16*)alloc((size_t)3 * 16384 * 2);
    bf16* xTt  = (bf16*)alloc((size_t)NB * 32 * 8192 * 2);        // 8 MiB
    bf16* hT0  = (bf16*)alloc((size_t)NB * 32 * 8192 * 2);        // 8 MiB
    bf16* hT1  = (bf16*)alloc((size_t)NB * 32 * 8192 * 2);        // 8 MiB
    bf16* adjT = (bf16*)alloc((size_t)NB * 16 * 32 * 8192 * 2);   // 128 MiB

    float* outF = (float*)d_out;

    prep_wt<<<3, 256, 0, stream>>>(W[0], W[1], W[2], WTg);
    prep_xt<<<256, 256, 0, stream>>>(x, xTt);

    fused_layer<1, false><<<256, 512, 0, stream>>>(adj, adjT, xTt, WTg,
                                                   bb[0], gg[0], be[0], hT0, nullptr);
    fused_layer<2, false><<<256, 512, 0, stream>>>(adj, adjT, hT0, WTg + 16384,
                                                   bb[1], gg[1], be[1], hT1, nullptr);
    fused_layer<2, true ><<<256, 512, 0, stream>>>(adj, adjT, hT1, WTg + 2 * 16384,
                                                   bb[2], gg[2], be[2], nullptr, outF);
}